// Round 1
// baseline (127.056 us; speedup 1.0000x reference)
//
#include <hip/hip_runtime.h>

#define GRID 32
#define NT 48
#define BLK 256
#define SPLIT 16                 // threads per point; each handles 3 t-rows = 9 tris
#define PPB (BLK / SPLIT)        // 16 points per block

// Per-edge packed info: bits [0]=base_x, [1]=base_y, [2]=base_z, [4:3]=axis.
// EDGE_BASE[e][axis[e]] == 0 for all 12 edges, so vert = base with comp[axis]=t.
#define EDGE_PACK ( (0ULL<<0) | (9ULL<<5) | (2ULL<<10) | (8ULL<<15) | \
                    (4ULL<<20) | (13ULL<<25) | (6ULL<<30) | (12ULL<<35) | \
                    (16ULL<<40) | (17ULL<<45) | (19ULL<<50) | (18ULL<<55) )

// Squared distance from p to triangle (a,b,c), computed entirely from the 6
// Gram entries of the p-relative vectors Ap=p-a, Bp=p-b, Cp=p-c:
//   AA=Ap.Ap  AB=Ap.Bp  AC=Ap.Cp  BB=Bp.Bp  BC=Bp.Cp  CC=Cp.Cp
// Identities: d1=ab.Ap=AA-AB  d2=ac.Ap=AA-AC  d3=ab.Bp=AB-BB  d4=ac.Bp=AB-BC
//             d5=ab.Cp=AC-BC  d6=ac.Cp=AC-CC  d4-d3=BB-BC  d5-d6=CC-BC
// Region cascade matches the reference order/conditions exactly. The closest
// point is kept in barycentric form lam=(u,v,w); mode=false regions use
// (1-v'-w', v', w') and mode=true regions use (0, 1-w', w'), which reproduces
// the reference's affine q even on eps-clamped degenerate denominators
// (e.g. a==b -> lam=(1,0,0) -> d2=AA, same as reference q=a). The distance is
// the PSD quadratic form lam^T G lam, so no garbage value can poison the min.
__device__ __forceinline__ float tri_dist_gram(float AA, float AB, float AC,
                                               float BB, float BC, float CC) {
    float d1 = AA - AB, d2 = AA - AC;
    float d3 = AB - BB, d4 = AB - BC;
    float d5 = AC - BC, d6 = AC - CC;
    float d43 = BB - BC;          // == d4 - d3
    float d56 = CC - BC;          // == d5 - d6
    float vc = d1 * d4 - d3 * d2;
    float vb = d5 * d2 - d1 * d6;
    float va = d3 * d6 - d5 * d4;

    bool cbc = (va <= 0.f) & (d43 >= 0.f) & (d56 >= 0.f);
    bool cac = (vb <= 0.f) & (d2 >= 0.f) & (d6 <= 0.f);
    bool ccc = (d6 >= 0.f) & (d5 <= d6);
    bool cab = (vc <= 0.f) & (d1 >= 0.f) & (d3 <= 0.f);
    bool cbb = (d3 >= 0.f) & (d4 <= d3);
    bool caa = (d1 <= 0.f) & (d2 <= 0.f);

    // Select numerators / denominator / mode through the reference cascade
    // (later region wins). nv is only consumed by mode=false regions, so it
    // needs no select in mode=true rows.
    float nv = vb, nw = vc, den = va + vb + vc;
    bool mode = false;
    nw = cbc ? d43 : nw;  den = cbc ? d43 + d56 : den;  mode = cbc ? true  : mode;
    nv = cac ? 0.f : nv;  nw = cac ? d2  : nw;  den = cac ? d2 - d6 : den;  mode = cac ? false : mode;
    nw = ccc ? 1.f : nw;  den = ccc ? 1.f : den;  mode = ccc ? true  : mode;
    nv = cab ? d1  : nv;  nw = cab ? 0.f : nw;  den = cab ? d1 - d3 : den;  mode = cab ? false : mode;
    nw = cbb ? 0.f : nw;  den = cbb ? 1.f : den;  mode = cbb ? true  : mode;
    nv = caa ? 0.f : nv;  nw = caa ? 0.f : nw;  den = caa ? 1.f : den;  mode = caa ? false : mode;

    // Single safe_div for all regions (reference eps semantics preserved).
    float dd  = (fabsf(den) > 1e-12f) ? den : 1e-12f;
    float inv = __builtin_amdgcn_rcpf(dd);
    float vp = nv * inv;
    float wp = nw * inv;
    float u = mode ? 0.f : 1.f - vp - wp;
    float v = mode ? 1.f - wp : vp;
    // d^2 = lam^T G lam with lam=(u,v,wp)
    float e1 = fmaf(AC, wp, fmaf(AB, v, AA * u));
    float e2 = fmaf(BC, wp, fmaf(BB, v, AB * u));
    float e3 = fmaf(CC, wp, fmaf(BC, v, AC * u));
    return fmaf(wp, e3, fmaf(v, e2, u * e1));
}

__global__ __launch_bounds__(BLK) void ptd_kernel(
    const float* __restrict__ offset,     // (3,33,33,33)
    const float* __restrict__ points,     // (N,3)
    const int*   __restrict__ tri_table,  // (48,3,3)
    float*       __restrict__ out,        // (32768,48)
    int n)
{
    __shared__ float4 v_s[PPB * 13];      // p-relative verts (12 used, stride 13)
    __shared__ float  gram[PPB * 144];    // 12x12 symmetric Gram per point
    __shared__ int2   goff[NT * 3];       // per (t,k): 6 packed 8-bit Gram indices

    const int tid = threadIdx.x;
    const int g   = blockIdx.x * BLK + tid;
    const int pt  = g >> 4;               // SPLIT=16
    const int grp = tid & 15;
    const int pl  = tid >> 4;             // point-local row (0..15)
    const bool active = (pt < n);

    // Per-block: pack the 6 Gram element-indices for each (t,k) triangle.
    if (tid < NT * 3) {
        int i = tri_table[tid * 3 + 0];
        int j = tri_table[tid * 3 + 1];
        int k = tri_table[tid * 3 + 2];
        int o0 = (i * 13) | ((i * 12 + j) << 8) | ((i * 12 + k) << 16);
        int o1 = (j * 13) | ((j * 12 + k) << 8) | ((k * 13) << 16);
        goff[tid] = make_int2(o0, o1);
    }

    float4 vi = make_float4(0.f, 0.f, 0.f, 0.f);
    int cx = 0, cy = 0, cz = 0;
    if (active) {
        float px = points[pt * 3 + 0];
        float py = points[pt * 3 + 1];
        float pz = points[pt * 3 + 2];
        cx = min(max((int)floorf(px), 0), GRID - 1);
        cy = min(max((int)floorf(py), 0), GRID - 1);
        cz = min(max((int)floorf(pz), 0), GRID - 1);
        if (grp < 12) {
            float lx = px - (float)cx;
            float ly = py - (float)cy;
            float lz = pz - (float)cz;
            // Thread grp gathers edge grp, stores local - vert (and keeps it).
            unsigned nib = (unsigned)(EDGE_PACK >> (5 * grp)) & 31u;
            int gx = cx + (int)(nib & 1u);
            int gy = cy + (int)((nib >> 1) & 1u);
            int gz = cz + (int)((nib >> 2) & 1u);
            int ax = (int)(nib >> 3);
            float t = offset[((ax * 33 + gx) * 33 + gy) * 33 + gz];
            float vx = (ax == 0) ? t : (float)(nib & 1u);
            float vy = (ax == 1) ? t : (float)((nib >> 1) & 1u);
            float vz = (ax == 2) ? t : (float)((nib >> 2) & 1u);
            vi = make_float4(lx - vx, ly - vy, lz - vz, 0.0f);
            v_s[pl * 13 + grp] = vi;
        }
    }
    __syncthreads();

    // Gram fill: thread grp (<12) computes dots (grp, grp+d mod 12), d=0..6.
    // Covers all 78 unique pairs (d=6 pairs computed twice, bitwise-identical).
    if (active && grp < 12) {
        float* gp = &gram[pl * 144];
        int j = grp;
#pragma unroll
        for (int d = 0; d < 7; d++) {
            float4 vj = v_s[pl * 13 + j];
            float dv = fmaf(vi.z, vj.z, fmaf(vi.y, vj.y, vi.x * vj.x));
            gp[grp * 12 + j] = dv;
            gp[j * 12 + grp] = dv;
            j = (j == 11) ? 0 : j + 1;
        }
    }
    __syncthreads();

    if (!active) return;

    const float* gp = &gram[pl * 144];
    float* outp = out + ((((cx * GRID) + cy) * GRID + cz) * NT);
    // Thread's 9 (t,k) index-pairs are contiguous: goff[grp*9 + r*3 + k].
    const int2* gofft = &goff[grp * 9];

#pragma unroll
    for (int r = 0; r < 3; r++) {
        float dmin;
#pragma unroll
        for (int k = 0; k < 3; k++) {
            int2 o = gofft[r * 3 + k];
            float AA = gp[o.x & 255];
            float AB = gp[(o.x >> 8) & 255];
            float AC = gp[(unsigned)o.x >> 16];
            float BB = gp[o.y & 255];
            float BC = gp[(o.y >> 8) & 255];
            float CC = gp[(unsigned)o.y >> 16];
            float d = tri_dist_gram(AA, AB, AC, BB, BC, CC);
            dmin = (k == 0) ? d : fminf(dmin, d);
        }
        atomicAdd(&outp[grp * 3 + r], dmin);
    }
}

extern "C" void kernel_launch(void* const* d_in, const int* in_sizes, int n_in,
                              void* d_out, int out_size, void* d_ws, size_t ws_size,
                              hipStream_t stream) {
    const float* offset    = (const float*)d_in[0];
    const float* points    = (const float*)d_in[1];
    const int*   tri_table = (const int*)d_in[2];
    float* out = (float*)d_out;
    int n = in_sizes[1] / 3;  // 131072 points

    // Output is accumulated via atomics; harness poisons d_out with 0xAA.
    hipMemsetAsync(d_out, 0, (size_t)out_size * sizeof(float), stream);

    long total = (long)n * SPLIT;
    int blocks = (int)((total + BLK - 1) / BLK);
    ptd_kernel<<<blocks, BLK, 0, stream>>>(offset, points, tri_table, out, n);
}